// Round 10
// baseline (317.552 us; speedup 1.0000x reference)
//
#include <hip/hip_runtime.h>
#include <stdint.h>

typedef __attribute__((ext_vector_type(4))) float f32x4;
typedef __attribute__((ext_vector_type(8))) short bf16x8;
typedef __attribute__((ext_vector_type(8))) unsigned short u16x8;
typedef __attribute__((ext_vector_type(2))) unsigned int u32x2;

#define B_SZ   32
#define L_AUD  441000
#define PAD_A  1024
#define LP     443048          // L_AUD + 2*PAD_A
#define T_FR   862
#define J_TOT  27584           // B_SZ * T_FR
#define JPAD   27648           // 216 * 128
#define F_BINS 1025
#define NFFT   2048
#define NB     64
#define FPAD   1152            // 9 * 128
#define NT_F   9
#define NT_J2  216             // 27648 / 128
#define NWG2   (NT_J2 * NT_F)  // 1944 = 8 * 243
#define ROWB   886096          // LP * 2 bytes per xbp row

// ---- fold-path ws layout -------------------------------------------------
#define W2_OFF     0
#define W2_BYTES   (NT_F * 32 * 16384)            // 4,718,592 (A frag-major)
#define GB2_OFF    W2_BYTES
#define GB2_BYTES  (NB * FPAD * 2)                // 147,456
#define UB_OFF     (GB2_OFF + GB2_BYTES)          // 4,866,048
#define UB_BYTES   ((size_t)JPAD * 2048 * 2)      // 113,246,208 (ubf frag-major)
#define WS_FOLD    (UB_OFF + UB_BYTES)            // 118,112,256
#define SLAB_BYTES ((size_t)NT_F * NB * JPAD * 4) // 63,700,992
#define WS_FOLD_SLAB (WS_FOLD + SLAB_BYTES)       // 181,813,248

// ---- fallback (round-5) ws layout ---------------------------------------
#define FB_XBP_OFF   0
#define FB_XBP_BYTES (B_SZ * LP * 2)              // 28,355,072
#define FB_WBT_OFF   FB_XBP_BYTES
#define FB_WBT_BYTES (NT_F * 32 * 2 * 16384)      // 9,437,184
#define FB_GB_OFF    (FB_WBT_OFF + FB_WBT_BYTES)
#define FB_WS_NEED   (FB_GB_OFF + GB2_BYTES)      // 37,939,712
#define FB_SLAB_OFF  FB_WS_NEED
#define FB_WS_BIG    ((size_t)FB_SLAB_OFF + SLAB_BYTES) // 101,640,704
#define FB_NT_J      108
#define FB_NWG       (FB_NT_J * NT_F)             // 972

__device__ __forceinline__ uint16_t f2bf(float f) {
  union { float f; uint32_t u; } c; c.f = f;
  uint32_t r = c.u + 0x7FFFu + ((c.u >> 16) & 1u);
  return (uint16_t)(r >> 16);
}
__device__ __forceinline__ float bf2f(uint32_t u) {
  union { uint32_t u; float f; } c; c.u = u << 16; return c.f;
}

__device__ __forceinline__ f32x4 mfma16(bf16x8 a, bf16x8 b, f32x4 c) {
  return __builtin_amdgcn_mfma_f32_16x16x32_bf16(a, b, c, 0, 0, 0);
}

#define GLD16(g, l) __builtin_amdgcn_global_load_lds( \
    (__attribute__((address_space(1))) void*)(g),     \
    (__attribute__((address_space(3))) void*)(l), 16, 0, 0)

__device__ __forceinline__ int refl(int p) {   // padded coord -> sample idx
  int s = p - PAD_A;
  s = s < 0 ? -s : s;
  s = s >= L_AUD ? (2 * L_AUD - 2 - s) : s;
  return s;
}

// ==== shared preps ========================================================

__global__ __launch_bounds__(256) void build_gb(const float* __restrict__ g,
                                                uint16_t* __restrict__ gb) {
  int i = blockIdx.x * 256 + threadIdx.x;
  int n = i / FPAD;
  int f = i - n * FPAD;
  gb[i] = f2bf(f < F_BINS ? g[n * F_BINS + f] : 0.0f);
}

__global__ __launch_bounds__(256) void reduce9(const float* __restrict__ slab,
                                               float* __restrict__ out) {
  int i = blockIdx.x * 256 + threadIdx.x;
  if (i >= J_TOT * NB) return;
  int b = i / (NB * T_FR);
  int rem = i - b * (NB * T_FR);
  int n = rem / T_FR;
  int t = rem - n * T_FR;
  int j = b * T_FR + t;
  float s = 0.f;
#pragma unroll
  for (int fb = 0; fb < NT_F; ++fb)
    s += slab[((size_t)fb * NB + n) * JPAD + j];
  out[i] = s;
}

// ==== fold-path preps (FRAG-MAJOR layouts for direct global->VGPR) ========

// A: frag id = (fb*32 + kkt)*16 + fm; lane L holds A[row=fm*16+(L&15)]
// [k=kkt*32+(L>>4)*8+e]; byte = frag*1024 + L*16 + e*2.
// rows 0..127 = cos, 128..255 = sin; f = fb*128+(row&127); k==0 -> w[f][1024]
__global__ __launch_bounds__(256) void build_wbt3(const float* __restrict__ wsin,
                                                  const float* __restrict__ wcos,
                                                  uint16_t* __restrict__ wbt) {
  int idx = blockIdx.x * 256 + threadIdx.x;   // 2,359,296 bf16 elements
  int e = idx & 7;
  int lane = (idx >> 3) & 63;
  int fm = (idx >> 9) & 15;
  int kkt = (idx >> 13) & 31;
  int fb = idx >> 18;
  int row = fm * 16 + (lane & 15);
  int k = kkt * 32 + ((lane >> 4) << 3) + e;
  int plane = row >> 7;                        // 0 cos, 1 sin
  int f = fb * 128 + (row & 127);
  float val = 0.f;
  if (f < F_BINS) {
    int mm = (k == 0) ? 1024 : k;
    val = plane ? wsin[(size_t)f * NFFT + mm] : wcos[(size_t)f * NFFT + mm];
  }
  wbt[idx] = f2bf(val);
}

// folded frames frag-major: frag id = (jt*32 + kkt)*2 + sign; lane L holds
// u[j=jt*16+(L&15)][k=kkt*32+(L>>4)*8+e]; byte = frag*1024 + L*16 + e*2.
// One 128-thread block per frame jg; tid covers k-range tid*8..+8.
__global__ __launch_bounds__(128) void build_ubf(const float* __restrict__ x,
                                                 uint16_t* __restrict__ ub) {
  __shared__ float xs[2048];
  int jg = blockIdx.x;
  int tid = threadIdx.x;
  int m0 = tid * 8;
  // dest: jt = jg>>4, kkt = m0>>5, lane = ((m0>>3)&3)*16 + (jg&15)
  size_t basef = (((size_t)(jg >> 4) * 32 + (m0 >> 5)) * 2) * 1024 +
                 (size_t)((((m0 >> 3) & 3) * 16 + (jg & 15)) * 16);
  if (jg >= J_TOT) {
    u16x8 z = (u16x8)0;
    *(u16x8*)((char*)ub + basef) = z;
    *(u16x8*)((char*)ub + basef + 1024) = z;
    return;
  }
  int b = jg / T_FR, t = jg - b * T_FR;
  int c = t * 512;
  const float* xb = x + (size_t)b * L_AUD;
  if (t >= 2 && t <= 859) {
    const float4* src = (const float4*)(xb + c - PAD_A);
    float4* dl = (float4*)xs;
#pragma unroll
    for (int i = 0; i < 4; ++i) dl[tid * 4 + i] = src[tid * 4 + i];
  } else {
#pragma unroll
    for (int i = 0; i < 16; ++i) xs[tid * 16 + i] = xb[refl(c + tid * 16 + i)];
  }
  __syncthreads();
  u16x8 vp, vm;
#pragma unroll
  for (int i = 0; i < 8; ++i) {
    int m = m0 + i;
    if (m == 0) { vp[i] = f2bf(xs[1024]); vm[i] = 0; }
    else {
      float a = xs[m], r = xs[2048 - m];
      vp[i] = f2bf(a + r);
      vm[i] = f2bf(a - r);
    }
  }
  *(u16x8*)((char*)ub + basef) = vp;          // sign 0 = u+ (cos)
  *(u16x8*)((char*)ub + basef + 1024) = vm;   // sign 1 = u- (sin)
}

// ==== fold main v2: barrier-free, LDS-free K-loop =========================
// Block 128f x 128j, 8 waves (plane x rw x jw), wave tile 64r x 64j.
// All frags loaded direct global->VGPR (coalesced 1KB/instr), 2-tile ping-pong.
#define SP1 __builtin_amdgcn_s_setprio(1)
#define SP0 __builtin_amdgcn_s_setprio(0)

template <bool USE_SLAB>
__global__ __launch_bounds__(512, 2) void gammatone_fold2(
    const char* __restrict__ ubf, const char* __restrict__ wbt3,
    const char* __restrict__ gb, float* __restrict__ dst) {
  __shared__ __align__(16) char smem[32768];   // epilogue spec tile only

  const int tid = threadIdx.x;
  const int w = tid >> 6, l = tid & 63;
  const int lgrp = l >> 4, l15 = l & 15;
  const int plane = w >> 2;          // 0 cos, 1 sin
  const int rw = (w >> 1) & 1;       // f 64-half
  const int jw = w & 1;              // j 64-half

  // XCD chunking, j-major (fb fastest): 1944 = 8 * 243 exact
  const int orig = blockIdx.x;
  const int wkid = (orig & 7) * 243 + (orig >> 3);
  const int jb = wkid / NT_F;
  const int fb = wkid - jb * NT_F;
  const int j0 = jb * 128;
  const int f0 = fb * 128;

  // A frag base: frags fm = plane*8 + rw*4 + m ; stride per kkt = 16KB, per m = 1KB
  const char* aB = wbt3 + (((size_t)fb * 32) * 16 + plane * 8 + rw * 4) * 1024
                        + (size_t)l * 16;
  // B frag base: j-tiles jt = jb*8 + jw*4 + n ; stride per kkt = 2KB, per n = 64KB
  const char* bB = ubf + (((size_t)(jb * 8 + jw * 4) * 32) * 2 + plane) * 1024
                       + (size_t)l * 16;

#define LOADT(kkt, av_, bv_) do {                                           \
    const char* a_ = aB + (size_t)(kkt) * 16384;                            \
    const char* b_ = bB + (size_t)(kkt) * 2048;                             \
    av_[0] = *(const bf16x8*)(a_);                                          \
    av_[1] = *(const bf16x8*)(a_ + 1024);                                   \
    av_[2] = *(const bf16x8*)(a_ + 2048);                                   \
    av_[3] = *(const bf16x8*)(a_ + 3072);                                   \
    bv_[0] = *(const bf16x8*)(b_);                                          \
    bv_[1] = *(const bf16x8*)(b_ + 65536);                                  \
    bv_[2] = *(const bf16x8*)(b_ + 131072);                                 \
    bv_[3] = *(const bf16x8*)(b_ + 196608);                                 \
  } while (0)

  f32x4 acc[4][4];
#pragma unroll
  for (int m = 0; m < 4; ++m)
#pragma unroll
    for (int n = 0; n < 4; ++n) acc[m][n] = (f32x4){0.f, 0.f, 0.f, 0.f};

#define MM(av_, bv_) do {                                                   \
    SP1;                                                                    \
    _Pragma("unroll")                                                       \
    for (int m = 0; m < 4; ++m)                                             \
      _Pragma("unroll")                                                     \
      for (int n = 0; n < 4; ++n)                                           \
        acc[m][n] = mfma16(av_[m], bv_[n], acc[m][n]);                      \
    SP0;                                                                    \
  } while (0)

  bf16x8 avA[4], bvA[4], avB[4], bvB[4];
  LOADT(0, avA, bvA);
  LOADT(1, avB, bvB);
  for (int kk = 0; kk < 30; kk += 2) {
    MM(avA, bvA);
    LOADT(kk + 2, avA, bvA);    // WAR on avA keeps this after MM; flies under MM(B)
    MM(avB, bvB);
    LOADT(kk + 3, avB, bvB);
  }
  MM(avA, bvA);
  MM(avB, bvB);

  // ---- epilogue: spec = cos^2 + sin^2 -> LDS [128 j][128 f] bf16 --------
  // off = j*256 + ((fi*2) ^ ((j&7)<<4)); acc (m,n,r): fi = rw*64+m*16+lgrp*4+r,
  // j = jw*64 + n*16 + l15
  __syncthreads();
  if (plane == 0) {
#pragma unroll
    for (int m = 0; m < 4; ++m) {
      int fi = rw * 64 + m * 16 + lgrp * 4;
#pragma unroll
      for (int n = 0; n < 4; ++n) {
        int j = jw * 64 + n * 16 + l15;
        f32x4 c = acc[m][n];
        uint32_t lo = (uint32_t)f2bf(c.x * c.x) |
                      ((uint32_t)f2bf(c.y * c.y) << 16);
        uint32_t hi = (uint32_t)f2bf(c.z * c.z) |
                      ((uint32_t)f2bf(c.w * c.w) << 16);
        int off = j * 256 + ((fi * 2) ^ ((j & 7) << 4));
        *(u32x2*)(smem + off) = (u32x2){lo, hi};
      }
    }
  }
  __syncthreads();
  if (plane == 1) {
#pragma unroll
    for (int m = 0; m < 4; ++m) {
      int fi = rw * 64 + m * 16 + lgrp * 4;
#pragma unroll
      for (int n = 0; n < 4; ++n) {
        int j = jw * 64 + n * 16 + l15;
        int off = j * 256 + ((fi * 2) ^ ((j & 7) << 4));
        u32x2 v = *(u32x2*)(smem + off);
        f32x4 s = acc[m][n];
        uint32_t lo = (uint32_t)f2bf(bf2f(v.x & 0xffffu) + s.x * s.x) |
                      ((uint32_t)f2bf(bf2f(v.x >> 16) + s.y * s.y) << 16);
        uint32_t hi = (uint32_t)f2bf(bf2f(v.y & 0xffffu) + s.z * s.z) |
                      ((uint32_t)f2bf(bf2f(v.y >> 16) + s.w * s.w) << 16);
        *(u32x2*)(smem + off) = (u32x2){lo, hi};
      }
    }
  }
  __syncthreads();

  // second GEMM: out_part[64][128j] = G[64][f0:+128] x spec[128][128]
  // wave w owns j strip [w*16, +16)
  f32x4 acc2[4];
#pragma unroll
  for (int m = 0; m < 4; ++m) acc2[m] = (f32x4){0.f, 0.f, 0.f, 0.f};
  const int jwq = w * 16;
#pragma unroll
  for (int ks = 0; ks < 4; ++ks) {
    bf16x8 gf[4], sf;
#pragma unroll
    for (int m2 = 0; m2 < 4; ++m2) {
      int grow = m2 * 16 + l15;
      gf[m2] = *(const bf16x8*)(gb + ((size_t)grow * FPAD + f0 + ks * 32 + lgrp * 8) * 2);
    }
    {
      int j = jwq + l15;
      sf = *(const bf16x8*)(smem + j * 256 + (((ks * 32 + lgrp * 8) * 2) ^ ((j & 7) << 4)));
    }
#pragma unroll
    for (int m2 = 0; m2 < 4; ++m2)
      acc2[m2] = mfma16(gf[m2], sf, acc2[m2]);
  }

  {
    int jg = j0 + jwq + l15;
    if (USE_SLAB) {
      float* sl = dst + ((size_t)fb * NB) * JPAD + jg;
#pragma unroll
      for (int m2 = 0; m2 < 4; ++m2)
#pragma unroll
        for (int r2 = 0; r2 < 4; ++r2) {
          int nout = m2 * 16 + lgrp * 4 + r2;
          sl[(size_t)nout * JPAD] = acc2[m2][r2];
        }
    } else if (jg < J_TOT) {
      int b = jg / T_FR;
      int t = jg - b * T_FR;
      float* ob = dst + (size_t)(b * NB) * T_FR + t;
#pragma unroll
      for (int m2 = 0; m2 < 4; ++m2)
#pragma unroll
        for (int r2 = 0; r2 < 4; ++r2) {
          int nout = m2 * 16 + lgrp * 4 + r2;
          atomicAdd(ob + (size_t)nout * T_FR, acc2[m2][r2]);
        }
    }
  }
}

// ==== fallback path (round-5 kernels, verbatim) ===========================

__global__ __launch_bounds__(256) void build_xbp(const float* __restrict__ x,
                                                 uint16_t* __restrict__ xbp) {
  int i = blockIdx.x * 256 + threadIdx.x;
  int b = i / LP;
  int p = i - b * LP;
  xbp[i] = f2bf(x[b * L_AUD + refl(p)]);
}

__global__ __launch_bounds__(256) void build_wbtf(const float* __restrict__ wsin,
                                                  const float* __restrict__ wcos,
                                                  uint16_t* __restrict__ wbt) {
  int idx = blockIdx.x * 256 + threadIdx.x;
  int e = idx & 7;
  int l = (idx >> 3) & 63;
  int s = (idx >> 9) & 1;
  int fm = (idx >> 10) & 15;
  int kkt = (idx >> 14) & 31;
  int fb = idx >> 19;
  int tr = fm * 16 + (l & 15);
  int k = kkt * 64 + s * 32 + ((l >> 4) << 3) + e;
  int plane = (tr >> 6) & 1;
  int f = fb * 128 + ((tr >> 7) << 6) + (tr & 63);
  float v = (f < F_BINS) ? (plane ? wcos[f * NFFT + k] : wsin[f * NFFT + k]) : 0.0f;
  wbt[idx] = f2bf(v);
}

__device__ __forceinline__ void load_a2(bf16x8 (&d)[2][2], const char* p) {
  d[0][0] = *(const bf16x8*)(p);
  d[0][1] = *(const bf16x8*)(p + 1024);
  d[1][0] = *(const bf16x8*)(p + 2048);
  d[1][1] = *(const bf16x8*)(p + 3072);
}
__device__ __forceinline__ void load_b4(bf16x8 (&dst)[4][2], const char* p,
                                        int k0, int k1) {
#pragma unroll
  for (int n = 0; n < 4; ++n) {
    dst[n][0] = *(const bf16x8*)(p + n * 2048 + k0);
    dst[n][1] = *(const bf16x8*)(p + n * 2048 + k1);
  }
}
__device__ __forceinline__ void mfma_pair(f32x4 (*ac)[4],
                                          const bf16x8 (&av)[2][2],
                                          const bf16x8 (&bv)[4][2]) {
#pragma unroll
  for (int m = 0; m < 2; ++m)
#pragma unroll
    for (int n = 0; n < 4; ++n) {
      ac[m][n] = mfma16(av[m][0], bv[n][0], ac[m][n]);
      ac[m][n] = mfma16(av[m][1], bv[n][1], ac[m][n]);
    }
}

template <bool USE_SLAB>
__global__ __launch_bounds__(512, 2) void gammatone_fb(
    const char* __restrict__ xbp, const char* __restrict__ wbt,
    const char* __restrict__ gb, float* __restrict__ dst) {
  __shared__ __align__(16) char smem[65536];

  const int tid = threadIdx.x;
  const int w = tid >> 6, l = tid & 63;
  const int lgrp = l >> 4, l15 = l & 15;
  const int wr = w >> 2, wc = w & 3;

  const int orig = blockIdx.y * FB_NT_J + blockIdx.x;
  const int xcd = orig & 7, slot = orig >> 3;
  const int q = FB_NWG / 8, r = FB_NWG & 7;
  const int wkid = (xcd < r ? xcd * (q + 1) : r * (q + 1) + (xcd - r) * q) + slot;
  const int fb = wkid / FB_NT_J;
  const int jb = wkid - fb * FB_NT_J;
  const int j0 = jb * 256;
  const int f0 = fb * 128;

  const int xr = (((tid & 7) << 4)) ^ ((((tid >> 3) & 7)) << 4);
  size_t fbase[2][2];
#pragma unroll
  for (int h = 0; h < 2; ++h)
#pragma unroll
    for (int i = 0; i < 2; ++i) {
      int col = j0 + h * 128 + i * 64 + (tid >> 3);
      if (col > J_TOT - 1) col = J_TOT - 1;
      int b = col / T_FR;
      int t = col - b * T_FR;
      fbase[h][i] = (size_t)b * ROWB + (size_t)t * 1024 + (size_t)xr;
    }

#define STAGE_B2(kkt, buf) do {                                             \
    char* d0_ = smem + (buf) * 32768;                                       \
    char* d1_ = smem + (buf) * 32768 + 16384;                               \
    GLD16(xbp + fbase[0][0] + (size_t)(kkt) * 128, d0_ + w * 1024 + l * 16);\
    GLD16(xbp + fbase[0][1] + (size_t)(kkt) * 128, d0_ + 8192 + w * 1024 + l * 16);\
    GLD16(xbp + fbase[1][0] + (size_t)(kkt) * 128, d1_ + w * 1024 + l * 16);\
    GLD16(xbp + fbase[1][1] + (size_t)(kkt) * 128, d1_ + 8192 + w * 1024 + l * 16);\
  } while (0)

  const int albase = l15 * 128;
  const int xa = (l15 & 7) << 4;
  const int k0 = (lgrp * 16) ^ xa;
  const int k1 = (64 + lgrp * 16) ^ xa;
  const int jrb = (wc & 1) * 64;
  const char* Bb0 = smem + (wc >> 1) * 16384 + jrb * 128 + albase;
  const char* Bb1 = Bb0 + 32768;
  const char* wbt_a = wbt + (size_t)fb * 32 * 32768 + wr * 16384 + (size_t)l * 16;

  STAGE_B2(0, 0);
  STAGE_B2(1, 1);
  asm volatile("s_waitcnt vmcnt(0)" ::: "memory");
  __builtin_amdgcn_s_barrier();

  f32x4 acc[8][4];
#pragma unroll
  for (int m = 0; m < 8; ++m)
#pragma unroll
    for (int n = 0; n < 4; ++n) acc[m][n] = (f32x4){0.f, 0.f, 0.f, 0.f};

  bf16x8 bvA[4][2], bvB[4][2], av0[2][2], av1[2][2];
  load_b4(bvA, Bb0, k0, k1);
  load_a2(av0, wbt_a);
  asm volatile("s_waitcnt lgkmcnt(0)" ::: "memory");
  __builtin_amdgcn_s_barrier();

#define TILEFB(KK, bvC, bvN, BbN, STG, NXT) do {                            \
    const char* aT = wbt_a + (size_t)(KK) * 32768;                          \
    if (STG) STAGE_B2((KK) + 2, (KK) & 1);                                  \
    load_a2(av1, aT + 2 * 2048);                                            \
    SP1; mfma_pair(&acc[0], av0, bvC); SP0;                                 \
    load_a2(av0, aT + 4 * 2048);                                            \
    SP1; mfma_pair(&acc[2], av1, bvC); SP0;                                 \
    load_a2(av1, aT + 6 * 2048);                                            \
    if (NXT) load_b4(bvN, BbN, k0, k1);                                     \
    SP1; mfma_pair(&acc[4], av0, bvC); SP0;                                 \
    if (NXT) load_a2(av0, wbt_a + (size_t)((KK) + 1) * 32768);              \
    SP1; mfma_pair(&acc[6], av1, bvC); SP0;                                 \
    asm volatile("s_waitcnt lgkmcnt(0)" ::: "memory");                      \
    __builtin_amdgcn_s_barrier();                                           \
  } while (0)

  for (int kk = 0; kk < 30; kk += 2) {
    TILEFB(kk,     bvA, bvB, Bb1, 1, 1);
    TILEFB(kk + 1, bvB, bvA, Bb0, 1, 1);
  }
  TILEFB(30, bvA, bvB, Bb1, 0, 1);
  TILEFB(31, bvB, bvA, Bb0, 0, 0);

  __syncthreads();
#pragma unroll
  for (int m = 0; m < 4; ++m) {
    int fi = wr * 64 + m * 16 + lgrp * 4;
#pragma unroll
    for (int n = 0; n < 4; ++n) {
      int j = wc * 64 + n * 16 + l15;
      f32x4 s = acc[m][n], c = acc[m + 4][n];
      uint32_t lo = (uint32_t)f2bf(s.x * s.x + c.x * c.x) |
                    ((uint32_t)f2bf(s.y * s.y + c.y * c.y) << 16);
      uint32_t hi = (uint32_t)f2bf(s.z * s.z + c.z * c.z) |
                    ((uint32_t)f2bf(s.w * s.w + c.w * c.w) << 16);
      int off = j * 256 + ((fi * 2) ^ ((j & 7) << 4));
      *(u32x2*)(smem + off) = (u32x2){lo, hi};
    }
  }
  __syncthreads();

  f32x4 acc2[4][2];
#pragma unroll
  for (int m = 0; m < 4; ++m) {
    acc2[m][0] = (f32x4){0.f, 0.f, 0.f, 0.f};
    acc2[m][1] = (f32x4){0.f, 0.f, 0.f, 0.f};
  }
  const int jw2 = w * 32;
#pragma unroll
  for (int ks = 0; ks < 4; ++ks) {
    bf16x8 gf[4], sf[2];
#pragma unroll
    for (int m2 = 0; m2 < 4; ++m2) {
      int grow = m2 * 16 + l15;
      gf[m2] = *(const bf16x8*)(gb + ((size_t)grow * FPAD + f0 + ks * 32 + lgrp * 8) * 2);
    }
#pragma unroll
    for (int nf = 0; nf < 2; ++nf) {
      int j = jw2 + nf * 16 + l15;
      sf[nf] = *(const bf16x8*)(smem + j * 256 + (((ks * 32 + lgrp * 8) * 2) ^ ((j & 7) << 4)));
    }
#pragma unroll
    for (int m2 = 0; m2 < 4; ++m2)
#pragma unroll
      for (int nf = 0; nf < 2; ++nf)
        acc2[m2][nf] = mfma16(gf[m2], sf[nf], acc2[m2][nf]);
  }

#pragma unroll
  for (int nf = 0; nf < 2; ++nf) {
    int jg = j0 + jw2 + nf * 16 + l15;
    if (USE_SLAB) {
      float* sl = dst + ((size_t)fb * NB) * JPAD + jg;
#pragma unroll
      for (int m2 = 0; m2 < 4; ++m2)
#pragma unroll
        for (int r2 = 0; r2 < 4; ++r2) {
          int nout = m2 * 16 + lgrp * 4 + r2;
          sl[(size_t)nout * JPAD] = acc2[m2][nf][r2];
        }
    } else if (jg < J_TOT) {
      int b = jg / T_FR;
      int t = jg - b * T_FR;
      float* ob = dst + (size_t)(b * NB) * T_FR + t;
#pragma unroll
      for (int m2 = 0; m2 < 4; ++m2)
#pragma unroll
        for (int r2 = 0; r2 < 4; ++r2) {
          int nout = m2 * 16 + lgrp * 4 + r2;
          atomicAdd(ob + (size_t)nout * T_FR, acc2[m2][nf][r2]);
        }
    }
  }
}

// ==== launcher ============================================================
extern "C" void kernel_launch(void* const* d_in, const int* in_sizes, int n_in,
                              void* d_out, int out_size, void* d_ws, size_t ws_size,
                              hipStream_t stream) {
  (void)in_sizes; (void)n_in;
  const float* x    = (const float*)d_in[0];
  const float* wsin = (const float*)d_in[1];
  const float* wcos = (const float*)d_in[2];
  const float* g    = (const float*)d_in[3];
  char* ws = (char*)d_ws;

  if (ws_size >= (size_t)WS_FOLD) {
    uint16_t* wbt3 = (uint16_t*)(ws + W2_OFF);
    uint16_t* gbp  = (uint16_t*)(ws + GB2_OFF);
    uint16_t* ubf  = (uint16_t*)(ws + UB_OFF);
    build_wbt3<<<(W2_BYTES / 2) / 256, 256, 0, stream>>>(wsin, wcos, wbt3);
    build_gb<<<(NB * FPAD) / 256, 256, 0, stream>>>(g, gbp);
    build_ubf<<<JPAD, 128, 0, stream>>>(x, ubf);
    if (ws_size >= (size_t)WS_FOLD_SLAB) {
      float* slab = (float*)(ws + WS_FOLD);
      gammatone_fold2<true><<<NWG2, 512, 0, stream>>>(
          (const char*)ubf, (const char*)wbt3, (const char*)gbp, slab);
      reduce9<<<(J_TOT * NB + 255) / 256, 256, 0, stream>>>(slab, (float*)d_out);
    } else {
      hipMemsetAsync(d_out, 0, (size_t)out_size * sizeof(float), stream);
      gammatone_fold2<false><<<NWG2, 512, 0, stream>>>(
          (const char*)ubf, (const char*)wbt3, (const char*)gbp, (float*)d_out);
    }
    return;
  }

  // fallback: round-5 path
  if (ws_size < (size_t)FB_WS_NEED) return;
  uint16_t* xbp = (uint16_t*)(ws + FB_XBP_OFF);
  uint16_t* wbt = (uint16_t*)(ws + FB_WBT_OFF);
  uint16_t* gbp = (uint16_t*)(ws + FB_GB_OFF);
  build_xbp<<<(B_SZ * LP) / 256, 256, 0, stream>>>(x, xbp);
  build_wbtf<<<(FB_WBT_BYTES / 2) / 256, 256, 0, stream>>>(wsin, wcos, wbt);
  build_gb<<<(NB * FPAD) / 256, 256, 0, stream>>>(g, gbp);
  if (ws_size >= (size_t)FB_WS_BIG) {
    float* slab = (float*)(ws + FB_SLAB_OFF);
    gammatone_fb<true><<<dim3(FB_NT_J, NT_F), 512, 0, stream>>>(
        (const char*)xbp, (const char*)wbt, (const char*)gbp, slab);
    reduce9<<<(J_TOT * NB + 255) / 256, 256, 0, stream>>>(slab, (float*)d_out);
  } else {
    hipMemsetAsync(d_out, 0, (size_t)out_size * sizeof(float), stream);
    gammatone_fb<false><<<dim3(FB_NT_J, NT_F), 512, 0, stream>>>(
        (const char*)xbp, (const char*)wbt, (const char*)gbp, (float*)d_out);
  }
}

// Round 11
// 291.562 us; speedup vs baseline: 1.0891x; 1.0891x over previous
//
#include <hip/hip_runtime.h>
#include <stdint.h>

typedef __attribute__((ext_vector_type(4))) float f32x4;
typedef __attribute__((ext_vector_type(16))) float f32x16;
typedef __attribute__((ext_vector_type(8))) short bf16x8;
typedef __attribute__((ext_vector_type(8))) unsigned short u16x8;
typedef __attribute__((ext_vector_type(4))) unsigned short u16x4;
typedef __attribute__((ext_vector_type(2))) unsigned int u32x2;

#define B_SZ   32
#define L_AUD  441000
#define PAD_A  1024
#define LP     443048
#define T_FR   862
#define J_TOT  27584
#define JPAD   27648           // 216 * 128 = 864 * 32
#define F_BINS 1025
#define NFFT   2048
#define NB     64
#define FPAD   1152
#define NT_F   9
#define NT_J2  216             // 27648 / 128
#define NWG2   (NT_J2 * NT_F)  // 1944 = 8 * 243
#define ROWB   886096

// ---- fold-path ws layout -------------------------------------------------
#define W2_OFF     0
#define W2_BYTES   (NT_F * 32 * 16384)            // 4,718,592 (A frag-major 32x32)
#define GB2_OFF    W2_BYTES
#define GB2_BYTES  (NB * FPAD * 2)                // 147,456
#define UB_OFF     (GB2_OFF + GB2_BYTES)
#define UB_BYTES   ((size_t)JPAD * 2048 * 2)      // 113,246,208 (ubf2 frag-major)
#define WS_FOLD    (UB_OFF + UB_BYTES)            // 118,112,256
#define SLAB_BYTES ((size_t)NT_F * NB * JPAD * 4) // 63,700,992
#define WS_FOLD_SLAB (WS_FOLD + SLAB_BYTES)       // 181,813,248

// ---- fallback (round-5) ws layout ---------------------------------------
#define FB_XBP_OFF   0
#define FB_XBP_BYTES (B_SZ * LP * 2)
#define FB_WBT_OFF   FB_XBP_BYTES
#define FB_WBT_BYTES (NT_F * 32 * 2 * 16384)
#define FB_GB_OFF    (FB_WBT_OFF + FB_WBT_BYTES)
#define FB_WS_NEED   (FB_GB_OFF + GB2_BYTES)
#define FB_SLAB_OFF  FB_WS_NEED
#define FB_WS_BIG    ((size_t)FB_SLAB_OFF + SLAB_BYTES)
#define FB_NT_J      108
#define FB_NWG       (FB_NT_J * NT_F)

__device__ __forceinline__ uint16_t f2bf(float f) {
  union { float f; uint32_t u; } c; c.f = f;
  uint32_t r = c.u + 0x7FFFu + ((c.u >> 16) & 1u);
  return (uint16_t)(r >> 16);
}
__device__ __forceinline__ float bf2u(uint16_t u) {
  union { uint32_t u; float f; } c; c.u = (uint32_t)u << 16; return c.f;
}

__device__ __forceinline__ f32x4 mfma16(bf16x8 a, bf16x8 b, f32x4 c) {
  return __builtin_amdgcn_mfma_f32_16x16x32_bf16(a, b, c, 0, 0, 0);
}
__device__ __forceinline__ f32x16 mfma32(bf16x8 a, bf16x8 b, f32x16 c) {
  return __builtin_amdgcn_mfma_f32_32x32x16_bf16(a, b, c, 0, 0, 0);
}

#define GLD16(g, l) __builtin_amdgcn_global_load_lds( \
    (__attribute__((address_space(1))) void*)(g),     \
    (__attribute__((address_space(3))) void*)(l), 16, 0, 0)

__device__ __forceinline__ int refl(int p) {
  int s = p - PAD_A;
  s = s < 0 ? -s : s;
  s = s >= L_AUD ? (2 * L_AUD - 2 - s) : s;
  return s;
}

#define SP1 __builtin_amdgcn_s_setprio(1)
#define SP0 __builtin_amdgcn_s_setprio(0)

// ==== shared preps ========================================================

__global__ __launch_bounds__(256) void build_gb(const float* __restrict__ g,
                                                uint16_t* __restrict__ gb) {
  int i = blockIdx.x * 256 + threadIdx.x;
  int n = i / FPAD;
  int f = i - n * FPAD;
  gb[i] = f2bf(f < F_BINS ? g[n * F_BINS + f] : 0.0f);
}

__global__ __launch_bounds__(256) void reduce9(const float* __restrict__ slab,
                                               float* __restrict__ out) {
  int i = blockIdx.x * 256 + threadIdx.x;
  if (i >= J_TOT * NB) return;
  int b = i / (NB * T_FR);
  int rem = i - b * (NB * T_FR);
  int n = rem / T_FR;
  int t = rem - n * T_FR;
  int j = b * T_FR + t;
  float s = 0.f;
#pragma unroll
  for (int fb = 0; fb < NT_F; ++fb)
    s += slab[((size_t)fb * NB + n) * JPAD + j];
  out[i] = s;
}

// ==== fold preps (frag-major, 32x32x16 fragments) =========================

// A (wbt4): idx = ((((fb*32+kkt)*2+sk)*8+rt)*64+l)*8+e ; byte = idx*2.
// lane l, reg e: plane = rt>>2 (0 cos, 1 sin), f = fb*128+(rt&3)*32+(l&31),
// k = kkt*32 + sk*16 + (l>>5)*8 + e ; k==0 -> w[f][1024]
__global__ __launch_bounds__(256) void build_wbt4(const float* __restrict__ wsin,
                                                  const float* __restrict__ wcos,
                                                  uint16_t* __restrict__ wbt) {
  int idx = blockIdx.x * 256 + threadIdx.x;   // 2,359,296
  int e = idx & 7;
  int l = (idx >> 3) & 63;
  int rt = (idx >> 9) & 7;
  int sk = (idx >> 12) & 1;
  int kkt = (idx >> 13) & 31;
  int fb = idx >> 18;
  int plane = rt >> 2;
  int f = fb * 128 + (rt & 3) * 32 + (l & 31);
  int k = kkt * 32 + sk * 16 + ((l >> 5) << 3) + e;
  float val = 0.f;
  if (f < F_BINS) {
    int mm = (k == 0) ? 1024 : k;
    val = plane ? wsin[(size_t)f * NFFT + mm] : wcos[(size_t)f * NFFT + mm];
  }
  wbt[idx] = f2bf(val);
}

// B (ubf2): frag id = ((jt*32 + kkt)*2 + sk)*2 + sign ; 1 KB frags.
// lane l holds u[sign][j = jt*32 + (l&31)][k = kkt*32 + sk*16 + (l>>5)*8 + e].
// One 128-thread block per frame jg; tid covers k = tid*8..+8.
__global__ __launch_bounds__(128) void build_ubf2(const float* __restrict__ x,
                                                  uint16_t* __restrict__ ub) {
  __shared__ float xs[2048];
  int jg = blockIdx.x;
  int tid = threadIdx.x;
  int m0 = tid * 8;
  int kkt = m0 >> 5, sk = (m0 >> 4) & 1, kh = (m0 >> 3) & 1;
  int lane = kh * 32 + (jg & 31);
  size_t base = ((((size_t)(jg >> 5) * 32 + kkt) * 2 + sk) * 2) * 1024 +
                (size_t)lane * 16;
  if (jg >= J_TOT) {
    u16x8 z = (u16x8)0;
    *(u16x8*)((char*)ub + base) = z;
    *(u16x8*)((char*)ub + base + 1024) = z;
    return;
  }
  int b = jg / T_FR, t = jg - b * T_FR;
  int c = t * 512;
  const float* xb = x + (size_t)b * L_AUD;
  if (t >= 2 && t <= 859) {
    const float4* src = (const float4*)(xb + c - PAD_A);
    float4* dl = (float4*)xs;
#pragma unroll
    for (int i = 0; i < 4; ++i) dl[tid * 4 + i] = src[tid * 4 + i];
  } else {
#pragma unroll
    for (int i = 0; i < 16; ++i) xs[tid * 16 + i] = xb[refl(c + tid * 16 + i)];
  }
  __syncthreads();
  u16x8 vp, vm;
#pragma unroll
  for (int i = 0; i < 8; ++i) {
    int m = m0 + i;
    if (m == 0) { vp[i] = f2bf(xs[1024]); vm[i] = 0; }
    else {
      float a = xs[m], r = xs[2048 - m];
      vp[i] = f2bf(a + r);
      vm[i] = f2bf(a - r);
    }
  }
  *(u16x8*)((char*)ub + base) = vp;          // sign 0 = u+ (cos)
  *(u16x8*)((char*)ub + base + 1024) = vm;   // sign 1 = u- (sin)
}

// ==== fold main v3: 256r x 128j, BK=32, 32x32x16 MFMA, 2 blocks/CU ========
template <bool USE_SLAB>
__global__ __launch_bounds__(512, 4) void gammatone_fold3(
    const char* __restrict__ ubf, const char* __restrict__ wbt4,
    const char* __restrict__ gb, float* __restrict__ dst) {
  __shared__ __align__(16) char smem[65536];   // 2 x {A 16K | B 16K}

  const int tid = threadIdx.x;
  const int w = tid >> 6, l = tid & 63;
  const int l31 = l & 31, lh = l >> 5;
  const int lgrp = l >> 4, l15 = l & 15;       // for GEMM2 (16x16 frags)
  const int plane = w >> 2;          // 0 cos, 1 sin
  const int rw = (w >> 1) & 1;       // rt-pair within plane
  const int jw = w & 1;              // jt-pair

  // XCD chunking, j-major (fb fastest): 1944 = 8 * 243 exact
  const int orig = blockIdx.x;
  const int wkid = (orig & 7) * 243 + (orig >> 3);
  const int jb = wkid / NT_F;
  const int fb = wkid - jb * NT_F;
  const int j0 = jb * 128;
  const int f0 = fb * 128;

  // staging: wave stages A bytes [w*2048,+2048) (2 glds) + 2 B frags (ii=w*2+{0,1})
  const char* wbtA = wbt4 + (size_t)fb * 524288;
  const int aSta = w * 2048 + l * 16;
  const int ii0 = w * 2, ii1 = w * 2 + 1;
  const char* bS0 = ubf + (size_t)(jb * 4 + (ii0 >> 2)) * 131072 + (ii0 & 3) * 1024 + l * 16;
  const char* bS1 = ubf + (size_t)(jb * 4 + (ii1 >> 2)) * 131072 + (ii1 & 3) * 1024 + l * 16;
  const int bD0 = 16384 + ii0 * 1024 + l * 16;
  const int bD1 = 16384 + ii1 * 1024 + l * 16;

#define STG(kkt, buf) do {                                                  \
    GLD16(wbtA + (size_t)(kkt) * 16384 + aSta,        smem + (buf) + aSta); \
    GLD16(wbtA + (size_t)(kkt) * 16384 + aSta + 1024, smem + (buf) + aSta + 1024); \
    GLD16(bS0 + (size_t)(kkt) * 4096, smem + (buf) + bD0);                  \
    GLD16(bS1 + (size_t)(kkt) * 4096, smem + (buf) + bD1);                  \
  } while (0)

  // frag-major LDS read offsets (lane-linear, conflict-free)
  int aof[2][2], bof[2][2];
#pragma unroll
  for (int m = 0; m < 2; ++m)
#pragma unroll
    for (int sk = 0; sk < 2; ++sk) {
      aof[m][sk] = (sk * 8 + plane * 4 + rw * 2 + m) * 1024 + l * 16;
      bof[m][sk] = 16384 + ((jw * 2 + m) * 4 + sk * 2 + plane) * 1024 + l * 16;
    }

  STG(0, 0);
  asm volatile("s_waitcnt vmcnt(0)" ::: "memory");
  __builtin_amdgcn_s_barrier();

  f32x16 acc[2][2];
#pragma unroll
  for (int m = 0; m < 2; ++m)
#pragma unroll
    for (int n = 0; n < 2; ++n) acc[m][n] = (f32x16)0.f;

  for (int kkt = 0; kkt < 32; ++kkt) {
    const int P = (kkt & 1) << 15;
    if (kkt < 31) STG(kkt + 1, P ^ 32768);
    bf16x8 av[2][2], bv[2][2];
#pragma unroll
    for (int m = 0; m < 2; ++m)
#pragma unroll
      for (int sk = 0; sk < 2; ++sk) {
        av[m][sk] = *(const bf16x8*)(smem + P + aof[m][sk]);
        bv[m][sk] = *(const bf16x8*)(smem + P + bof[m][sk]);
      }
    SP1;
#pragma unroll
    for (int m = 0; m < 2; ++m)
#pragma unroll
      for (int n = 0; n < 2; ++n) {
        acc[m][n] = mfma32(av[m][0], bv[n][0], acc[m][n]);
        acc[m][n] = mfma32(av[m][1], bv[n][1], acc[m][n]);
      }
    SP0;
    asm volatile("s_waitcnt lgkmcnt(0)" ::: "memory");
    if (kkt < 31) asm volatile("s_waitcnt vmcnt(0)" ::: "memory");
    __builtin_amdgcn_s_barrier();
  }

  // ---- epilogue: spec = cos^2 + sin^2 -> LDS [128 j][128 f] bf16 --------
  // 32x32 C/D: col j' = l&31, row = (reg&3) + 8*(reg>>2) + 4*(l>>5)
  __syncthreads();
  if (plane == 0) {
#pragma unroll
    for (int m = 0; m < 2; ++m)
#pragma unroll
      for (int n = 0; n < 2; ++n) {
        int j = (jw * 2 + n) * 32 + l31;
        int xs = (j & 7) << 4;
#pragma unroll
        for (int qd = 0; qd < 4; ++qd) {
          int fq = (rw * 2 + m) * 32 + qd * 8 + lh * 4;
          float v0 = acc[m][n][qd * 4 + 0], v1 = acc[m][n][qd * 4 + 1];
          float v2 = acc[m][n][qd * 4 + 2], v3 = acc[m][n][qd * 4 + 3];
          u16x4 pk = {f2bf(v0 * v0), f2bf(v1 * v1), f2bf(v2 * v2), f2bf(v3 * v3)};
          *(u16x4*)(smem + j * 256 + ((fq * 2) ^ xs)) = pk;
        }
      }
  }
  __syncthreads();
  if (plane == 1) {
#pragma unroll
    for (int m = 0; m < 2; ++m)
#pragma unroll
      for (int n = 0; n < 2; ++n) {
        int j = (jw * 2 + n) * 32 + l31;
        int xs = (j & 7) << 4;
#pragma unroll
        for (int qd = 0; qd < 4; ++qd) {
          int fq = (rw * 2 + m) * 32 + qd * 8 + lh * 4;
          char* p = smem + j * 256 + ((fq * 2) ^ xs);
          u16x4 old = *(u16x4*)p;
          float v0 = acc[m][n][qd * 4 + 0], v1 = acc[m][n][qd * 4 + 1];
          float v2 = acc[m][n][qd * 4 + 2], v3 = acc[m][n][qd * 4 + 3];
          u16x4 pk = {f2bf(bf2u(old[0]) + v0 * v0), f2bf(bf2u(old[1]) + v1 * v1),
                      f2bf(bf2u(old[2]) + v2 * v2), f2bf(bf2u(old[3]) + v3 * v3)};
          *(u16x4*)p = pk;
        }
      }
  }
  __syncthreads();

  // second GEMM (16x16x32): out_part[64][128j] = G[64][f0:+128] x spec[128][128]
  f32x4 acc2[4];
#pragma unroll
  for (int m = 0; m < 4; ++m) acc2[m] = (f32x4){0.f, 0.f, 0.f, 0.f};
  const int jwq = w * 16;
#pragma unroll
  for (int ks = 0; ks < 4; ++ks) {
    bf16x8 gf[4], sf;
#pragma unroll
    for (int m2 = 0; m2 < 4; ++m2) {
      int grow = m2 * 16 + l15;
      gf[m2] = *(const bf16x8*)(gb + ((size_t)grow * FPAD + f0 + ks * 32 + lgrp * 8) * 2);
    }
    {
      int j = jwq + l15;
      sf = *(const bf16x8*)(smem + j * 256 + (((ks * 32 + lgrp * 8) * 2) ^ ((j & 7) << 4)));
    }
#pragma unroll
    for (int m2 = 0; m2 < 4; ++m2)
      acc2[m2] = mfma16(gf[m2], sf, acc2[m2]);
  }

  {
    int jg = j0 + jwq + l15;
    if (USE_SLAB) {
      float* sl = dst + ((size_t)fb * NB) * JPAD + jg;
#pragma unroll
      for (int m2 = 0; m2 < 4; ++m2)
#pragma unroll
        for (int r2 = 0; r2 < 4; ++r2) {
          int nout = m2 * 16 + lgrp * 4 + r2;
          sl[(size_t)nout * JPAD] = acc2[m2][r2];
        }
    } else if (jg < J_TOT) {
      int b = jg / T_FR;
      int t = jg - b * T_FR;
      float* ob = dst + (size_t)(b * NB) * T_FR + t;
#pragma unroll
      for (int m2 = 0; m2 < 4; ++m2)
#pragma unroll
        for (int r2 = 0; r2 < 4; ++r2) {
          int nout = m2 * 16 + lgrp * 4 + r2;
          atomicAdd(ob + (size_t)nout * T_FR, acc2[m2][r2]);
        }
    }
  }
}

// ==== fallback path (round-5 kernels, verbatim) ===========================

__global__ __launch_bounds__(256) void build_xbp(const float* __restrict__ x,
                                                 uint16_t* __restrict__ xbp) {
  int i = blockIdx.x * 256 + threadIdx.x;
  int b = i / LP;
  int p = i - b * LP;
  xbp[i] = f2bf(x[b * L_AUD + refl(p)]);
}

__global__ __launch_bounds__(256) void build_wbtf(const float* __restrict__ wsin,
                                                  const float* __restrict__ wcos,
                                                  uint16_t* __restrict__ wbt) {
  int idx = blockIdx.x * 256 + threadIdx.x;
  int e = idx & 7;
  int l = (idx >> 3) & 63;
  int s = (idx >> 9) & 1;
  int fm = (idx >> 10) & 15;
  int kkt = (idx >> 14) & 31;
  int fb = idx >> 19;
  int tr = fm * 16 + (l & 15);
  int k = kkt * 64 + s * 32 + ((l >> 4) << 3) + e;
  int plane = (tr >> 6) & 1;
  int f = fb * 128 + ((tr >> 7) << 6) + (tr & 63);
  float v = (f < F_BINS) ? (plane ? wcos[f * NFFT + k] : wsin[f * NFFT + k]) : 0.0f;
  wbt[idx] = f2bf(v);
}

__device__ __forceinline__ void load_a2(bf16x8 (&d)[2][2], const char* p) {
  d[0][0] = *(const bf16x8*)(p);
  d[0][1] = *(const bf16x8*)(p + 1024);
  d[1][0] = *(const bf16x8*)(p + 2048);
  d[1][1] = *(const bf16x8*)(p + 3072);
}
__device__ __forceinline__ void load_b4(bf16x8 (&dst)[4][2], const char* p,
                                        int k0, int k1) {
#pragma unroll
  for (int n = 0; n < 4; ++n) {
    dst[n][0] = *(const bf16x8*)(p + n * 2048 + k0);
    dst[n][1] = *(const bf16x8*)(p + n * 2048 + k1);
  }
}
__device__ __forceinline__ void mfma_pair(f32x4 (*ac)[4],
                                          const bf16x8 (&av)[2][2],
                                          const bf16x8 (&bv)[4][2]) {
#pragma unroll
  for (int m = 0; m < 2; ++m)
#pragma unroll
    for (int n = 0; n < 4; ++n) {
      ac[m][n] = mfma16(av[m][0], bv[n][0], ac[m][n]);
      ac[m][n] = mfma16(av[m][1], bv[n][1], ac[m][n]);
    }
}

template <bool USE_SLAB>
__global__ __launch_bounds__(512, 2) void gammatone_fb(
    const char* __restrict__ xbp, const char* __restrict__ wbt,
    const char* __restrict__ gb, float* __restrict__ dst) {
  __shared__ __align__(16) char smem[65536];

  const int tid = threadIdx.x;
  const int w = tid >> 6, l = tid & 63;
  const int lgrp = l >> 4, l15 = l & 15;
  const int wr = w >> 2, wc = w & 3;

  const int orig = blockIdx.y * FB_NT_J + blockIdx.x;
  const int xcd = orig & 7, slot = orig >> 3;
  const int q = FB_NWG / 8, r = FB_NWG & 7;
  const int wkid = (xcd < r ? xcd * (q + 1) : r * (q + 1) + (xcd - r) * q) + slot;
  const int fb = wkid / FB_NT_J;
  const int jb = wkid - fb * FB_NT_J;
  const int j0 = jb * 256;
  const int f0 = fb * 128;

  const int xr = (((tid & 7) << 4)) ^ ((((tid >> 3) & 7)) << 4);
  size_t fbase[2][2];
#pragma unroll
  for (int h = 0; h < 2; ++h)
#pragma unroll
    for (int i = 0; i < 2; ++i) {
      int col = j0 + h * 128 + i * 64 + (tid >> 3);
      if (col > J_TOT - 1) col = J_TOT - 1;
      int b = col / T_FR;
      int t = col - b * T_FR;
      fbase[h][i] = (size_t)b * ROWB + (size_t)t * 1024 + (size_t)xr;
    }

#define STAGE_B2(kkt, buf) do {                                             \
    char* d0_ = smem + (buf) * 32768;                                       \
    char* d1_ = smem + (buf) * 32768 + 16384;                               \
    GLD16(xbp + fbase[0][0] + (size_t)(kkt) * 128, d0_ + w * 1024 + l * 16);\
    GLD16(xbp + fbase[0][1] + (size_t)(kkt) * 128, d0_ + 8192 + w * 1024 + l * 16);\
    GLD16(xbp + fbase[1][0] + (size_t)(kkt) * 128, d1_ + w * 1024 + l * 16);\
    GLD16(xbp + fbase[1][1] + (size_t)(kkt) * 128, d1_ + 8192 + w * 1024 + l * 16);\
  } while (0)

  const int albase = l15 * 128;
  const int xa = (l15 & 7) << 4;
  const int k0 = (lgrp * 16) ^ xa;
  const int k1 = (64 + lgrp * 16) ^ xa;
  const int jrb = (wc & 1) * 64;
  const char* Bb0 = smem + (wc >> 1) * 16384 + jrb * 128 + albase;
  const char* Bb1 = Bb0 + 32768;
  const char* wbt_a = wbt + (size_t)fb * 32 * 32768 + wr * 16384 + (size_t)l * 16;

  STAGE_B2(0, 0);
  STAGE_B2(1, 1);
  asm volatile("s_waitcnt vmcnt(0)" ::: "memory");
  __builtin_amdgcn_s_barrier();

  f32x4 acc[8][4];
#pragma unroll
  for (int m = 0; m < 8; ++m)
#pragma unroll
    for (int n = 0; n < 4; ++n) acc[m][n] = (f32x4){0.f, 0.f, 0.f, 0.f};

  bf16x8 bvA[4][2], bvB[4][2], av0[2][2], av1[2][2];
  load_b4(bvA, Bb0, k0, k1);
  load_a2(av0, wbt_a);
  asm volatile("s_waitcnt lgkmcnt(0)" ::: "memory");
  __builtin_amdgcn_s_barrier();

#define TILEFB(KK, bvC, bvN, BbN, STG_, NXT) do {                           \
    const char* aT = wbt_a + (size_t)(KK) * 32768;                          \
    if (STG_) STAGE_B2((KK) + 2, (KK) & 1);                                 \
    load_a2(av1, aT + 2 * 2048);                                            \
    SP1; mfma_pair(&acc[0], av0, bvC); SP0;                                 \
    load_a2(av0, aT + 4 * 2048);                                            \
    SP1; mfma_pair(&acc[2], av1, bvC); SP0;                                 \
    load_a2(av1, aT + 6 * 2048);                                            \
    if (NXT) load_b4(bvN, BbN, k0, k1);                                     \
    SP1; mfma_pair(&acc[4], av0, bvC); SP0;                                 \
    if (NXT) load_a2(av0, wbt_a + (size_t)((KK) + 1) * 32768);              \
    SP1; mfma_pair(&acc[6], av1, bvC); SP0;                                 \
    asm volatile("s_waitcnt lgkmcnt(0)" ::: "memory");                      \
    __builtin_amdgcn_s_barrier();                                           \
  } while (0)

  for (int kk = 0; kk < 30; kk += 2) {
    TILEFB(kk,     bvA, bvB, Bb1, 1, 1);
    TILEFB(kk + 1, bvB, bvA, Bb0, 1, 1);
  }
  TILEFB(30, bvA, bvB, Bb1, 0, 1);
  TILEFB(31, bvB, bvA, Bb0, 0, 0);

  __syncthreads();
#pragma unroll
  for (int m = 0; m < 4; ++m) {
    int fi = wr * 64 + m * 16 + lgrp * 4;
#pragma unroll
    for (int n = 0; n < 4; ++n) {
      int j = wc * 64 + n * 16 + l15;
      f32x4 s = acc[m][n], c = acc[m + 4][n];
      uint32_t lo = (uint32_t)f2bf(s.x * s.x + c.x * c.x) |
                    ((uint32_t)f2bf(s.y * s.y + c.y * c.y) << 16);
      uint32_t hi = (uint32_t)f2bf(s.z * s.z + c.z * c.z) |
                    ((uint32_t)f2bf(s.w * s.w + c.w * c.w) << 16);
      int off = j * 256 + ((fi * 2) ^ ((j & 7) << 4));
      *(u32x2*)(smem + off) = (u32x2){lo, hi};
    }
  }
  __syncthreads();

  f32x4 acc2[4][2];
#pragma unroll
  for (int m = 0; m < 4; ++m) {
    acc2[m][0] = (f32x4){0.f, 0.f, 0.f, 0.f};
    acc2[m][1] = (f32x4){0.f, 0.f, 0.f, 0.f};
  }
  const int jw2 = w * 32;
#pragma unroll
  for (int ks = 0; ks < 4; ++ks) {
    bf16x8 gf[4], sf[2];
#pragma unroll
    for (int m2 = 0; m2 < 4; ++m2) {
      int grow = m2 * 16 + l15;
      gf[m2] = *(const bf16x8*)(gb + ((size_t)grow * FPAD + f0 + ks * 32 + lgrp * 8) * 2);
    }
#pragma unroll
    for (int nf = 0; nf < 2; ++nf) {
      int j = jw2 + nf * 16 + l15;
      sf[nf] = *(const bf16x8*)(smem + j * 256 + (((ks * 32 + lgrp * 8) * 2) ^ ((j & 7) << 4)));
    }
#pragma unroll
    for (int m2 = 0; m2 < 4; ++m2)
#pragma unroll
      for (int nf = 0; nf < 2; ++nf)
        acc2[m2][nf] = mfma16(gf[m2], sf[nf], acc2[m2][nf]);
  }

#pragma unroll
  for (int nf = 0; nf < 2; ++nf) {
    int jg = j0 + jw2 + nf * 16 + l15;
    if (USE_SLAB) {
      float* sl = dst + ((size_t)fb * NB) * JPAD + jg;
#pragma unroll
      for (int m2 = 0; m2 < 4; ++m2)
#pragma unroll
        for (int r2 = 0; r2 < 4; ++r2) {
          int nout = m2 * 16 + lgrp * 4 + r2;
          sl[(size_t)nout * JPAD] = acc2[m2][nf][r2];
        }
    } else if (jg < J_TOT) {
      int b = jg / T_FR;
      int t = jg - b * T_FR;
      float* ob = dst + (size_t)(b * NB) * T_FR + t;
#pragma unroll
      for (int m2 = 0; m2 < 4; ++m2)
#pragma unroll
        for (int r2 = 0; r2 < 4; ++r2) {
          int nout = m2 * 16 + lgrp * 4 + r2;
          atomicAdd(ob + (size_t)nout * T_FR, acc2[m2][nf][r2]);
        }
    }
  }
}

// ==== launcher ============================================================
extern "C" void kernel_launch(void* const* d_in, const int* in_sizes, int n_in,
                              void* d_out, int out_size, void* d_ws, size_t ws_size,
                              hipStream_t stream) {
  (void)in_sizes; (void)n_in;
  const float* x    = (const float*)d_in[0];
  const float* wsin = (const float*)d_in[1];
  const float* wcos = (const float*)d_in[2];
  const float* g    = (const float*)d_in[3];
  char* ws = (char*)d_ws;

  if (ws_size >= (size_t)WS_FOLD) {
    uint16_t* wbt4 = (uint16_t*)(ws + W2_OFF);
    uint16_t* gbp  = (uint16_t*)(ws + GB2_OFF);
    uint16_t* ubf  = (uint16_t*)(ws + UB_OFF);
    build_wbt4<<<(W2_BYTES / 2) / 256, 256, 0, stream>>>(wsin, wcos, wbt4);
    build_gb<<<(NB * FPAD) / 256, 256, 0, stream>>>(g, gbp);
    build_ubf2<<<JPAD, 128, 0, stream>>>(x, ubf);
    if (ws_size >= (size_t)WS_FOLD_SLAB) {
      float* slab = (float*)(ws + WS_FOLD);
      gammatone_fold3<true><<<NWG2, 512, 0, stream>>>(
          (const char*)ubf, (const char*)wbt4, (const char*)gbp, slab);
      reduce9<<<(J_TOT * NB + 255) / 256, 256, 0, stream>>>(slab, (float*)d_out);
    } else {
      hipMemsetAsync(d_out, 0, (size_t)out_size * sizeof(float), stream);
      gammatone_fold3<false><<<NWG2, 512, 0, stream>>>(
          (const char*)ubf, (const char*)wbt4, (const char*)gbp, (float*)d_out);
    }
    return;
  }

  // fallback: round-5 path
  if (ws_size < (size_t)FB_WS_NEED) return;
  uint16_t* xbp = (uint16_t*)(ws + FB_XBP_OFF);
  uint16_t* wbt = (uint16_t*)(ws + FB_WBT_OFF);
  uint16_t* gbp = (uint16_t*)(ws + FB_GB_OFF);
  build_xbp<<<(B_SZ * LP) / 256, 256, 0, stream>>>(x, xbp);
  build_wbtf<<<(FB_WBT_BYTES / 2) / 256, 256, 0, stream>>>(wsin, wcos, wbt);
  build_gb<<<(NB * FPAD) / 256, 256, 0, stream>>>(g, gbp);
  if (ws_size >= (size_t)FB_WS_BIG) {
    float* slab = (float*)(ws + FB_SLAB_OFF);
    gammatone_fb<true><<<dim3(FB_NT_J, NT_F), 512, 0, stream>>>(
        (const char*)xbp, (const char*)wbt, (const char*)gbp, slab);
    reduce9<<<(J_TOT * NB + 255) / 256, 256, 0, stream>>>(slab, (float*)d_out);
  } else {
    hipMemsetAsync(d_out, 0, (size_t)out_size * sizeof(float), stream);
    gammatone_fb<false><<<dim3(FB_NT_J, NT_F), 512, 0, stream>>>(
        (const char*)xbp, (const char*)wbt, (const char*)gbp, (float*)d_out);
  }
}

// Round 13
// 215.011 us; speedup vs baseline: 1.4769x; 1.3560x over previous
//
#include <hip/hip_runtime.h>
#include <stdint.h>

typedef __attribute__((ext_vector_type(4))) float f32x4;
typedef __attribute__((ext_vector_type(8))) short bf16x8;
typedef __attribute__((ext_vector_type(8))) unsigned short u16x8;
typedef __attribute__((ext_vector_type(2))) unsigned int u32x2;

#define B_SZ   32
#define L_AUD  441000
#define PAD_A  1024
#define LP     443048          // L_AUD + 2*PAD_A
#define T_FR   862
#define J_TOT  27584           // B_SZ * T_FR
#define JPAD   27648           // 108 * 256
#define F_BINS 1025
#define NFFT   2048
#define NB     64
#define FPAD   1152            // 9 * 128
#define NT_J   108
#define NT_F   9
#define NWG    (NT_J * NT_F)   // 972
#define FB_NT_J NT_J
#define FB_NWG  NWG
#define ROWB   886096          // LP * 2 bytes per xbp row

// ---- fold-path ws layout -------------------------------------------------
#define W2_OFF     0
#define W2_BYTES   (NT_F * 32 * 16384)            // 4,718,592 (A blobs, K=1024)
#define GB2_OFF    W2_BYTES
#define GB2_BYTES  (NB * FPAD * 2)                // 147,456
#define UB_OFF     (GB2_OFF + GB2_BYTES)          // 4,866,048
#define UB_BYTES   ((size_t)JPAD * 2048 * 2)      // 113,246,208 (u+/u- bf16)
#define WS_FOLD    (UB_OFF + UB_BYTES)            // 118,112,256
#define SLAB_BYTES ((size_t)NT_F * NB * JPAD * 4) // 63,700,992
#define WS_FOLD_SLAB (WS_FOLD + SLAB_BYTES)       // 181,813,248

// ---- fallback (round-5) ws layout ---------------------------------------
#define FB_XBP_OFF   0
#define FB_XBP_BYTES (B_SZ * LP * 2)              // 28,355,072
#define FB_WBT_OFF   FB_XBP_BYTES
#define FB_WBT_BYTES (NT_F * 32 * 2 * 16384)      // 9,437,184
#define FB_GB_OFF    (FB_WBT_OFF + FB_WBT_BYTES)
#define FB_WS_NEED   (FB_GB_OFF + GB2_BYTES)      // 37,939,712
#define FB_SLAB_OFF  FB_WS_NEED
#define FB_WS_BIG    ((size_t)FB_SLAB_OFF + SLAB_BYTES) // 101,640,704

__device__ __forceinline__ uint16_t f2bf(float f) {
  union { float f; uint32_t u; } c; c.f = f;
  uint32_t r = c.u + 0x7FFFu + ((c.u >> 16) & 1u);
  return (uint16_t)(r >> 16);
}

__device__ __forceinline__ f32x4 mfma16(bf16x8 a, bf16x8 b, f32x4 c) {
  return __builtin_amdgcn_mfma_f32_16x16x32_bf16(a, b, c, 0, 0, 0);
}

#define GLD16(g, l) __builtin_amdgcn_global_load_lds( \
    (__attribute__((address_space(1))) void*)(g),     \
    (__attribute__((address_space(3))) void*)(l), 16, 0, 0)

__device__ __forceinline__ int refl(int p) {   // padded coord -> sample idx
  int s = p - PAD_A;
  s = s < 0 ? -s : s;
  s = s >= L_AUD ? (2 * L_AUD - 2 - s) : s;
  return s;
}

// ==== shared preps ========================================================

__global__ __launch_bounds__(256) void build_gb(const float* __restrict__ g,
                                                uint16_t* __restrict__ gb) {
  int i = blockIdx.x * 256 + threadIdx.x;
  int n = i / FPAD;
  int f = i - n * FPAD;
  gb[i] = f2bf(f < F_BINS ? g[n * F_BINS + f] : 0.0f);
}

__global__ __launch_bounds__(256) void reduce9(const float* __restrict__ slab,
                                               float* __restrict__ out) {
  int i = blockIdx.x * 256 + threadIdx.x;
  if (i >= J_TOT * NB) return;
  int b = i / (NB * T_FR);
  int rem = i - b * (NB * T_FR);
  int n = rem / T_FR;
  int t = rem - n * T_FR;
  int j = b * T_FR + t;
  float s = 0.f;
#pragma unroll
  for (int fb = 0; fb < NT_F; ++fb)
    s += slab[((size_t)fb * NB + n) * JPAD + j];
  out[i] = s;
}

// ==== fold-path preps =====================================================

// A blobs, K'=1024, PAIR-SWIZZLED: blob (fb,kkt) = 16KB, 128 rowpairs x 128B.
// byte(r,k) = (r>>1)*128 + (((k>>3)|((r&1)<<2)) ^ ((r>>1)&7))*16 + (k&7)*2
// rows 0..127 = cos, 128..255 = sin; f = fb*128+(r&127); m = kkt*32+k (m==0 -> w[f][1024])
__global__ __launch_bounds__(256) void build_wbt2(const float* __restrict__ wsin,
                                                  const float* __restrict__ wcos,
                                                  uint16_t* __restrict__ wbt) {
  int idx = blockIdx.x * 256 + threadIdx.x;   // 2,359,296 bf16 elements
  int e = idx & 7;
  int s = (idx >> 3) & 7;
  int jp = (idx >> 6) & 127;
  int kkt = (idx >> 13) & 31;
  int fb = idx >> 18;
  int v = s ^ (jp & 7);
  int r = jp * 2 + (v >> 2);
  int k = (v & 3) * 8 + e;
  int plane = r >> 7;                          // 0 cos, 1 sin
  int f = fb * 128 + (r & 127);
  int m = kkt * 32 + k;
  float val = 0.f;
  if (f < F_BINS) {
    int mm = (m == 0) ? 1024 : m;
    val = plane ? wsin[(size_t)f * NFFT + mm] : wcos[(size_t)f * NFFT + mm];
  }
  wbt[idx] = f2bf(val);
}

// folded frames: ub[j][sign][1024] bf16 (layout unchanged; fold staging
// pre-swizzles its per-lane SOURCE address). One 128-thread block per frame,
// window staged to LDS via coalesced float4.
__global__ __launch_bounds__(128) void build_ub(const float* __restrict__ x,
                                                uint16_t* __restrict__ ub) {
  __shared__ float xs[2048];
  int jg = blockIdx.x;
  int tid = threadIdx.x;
  uint16_t* outp = ub + (size_t)jg * 2048;
  if (jg >= J_TOT) {
    u16x8 z = (u16x8)0;
    *(u16x8*)(outp + tid * 8) = z;
    *(u16x8*)(outp + 1024 + tid * 8) = z;
    return;
  }
  int b = jg / T_FR, t = jg - b * T_FR;
  int c = t * 512;
  const float* xb = x + (size_t)b * L_AUD;
  if (t >= 2 && t <= 859) {
    const float4* src = (const float4*)(xb + c - PAD_A);
    float4* dl = (float4*)xs;
#pragma unroll
    for (int i = 0; i < 4; ++i) dl[tid * 4 + i] = src[tid * 4 + i];
  } else {
#pragma unroll
    for (int i = 0; i < 16; ++i) xs[tid * 16 + i] = xb[refl(c + tid * 16 + i)];
  }
  __syncthreads();
  int m0 = tid * 8;
  u16x8 vp, vm;
#pragma unroll
  for (int i = 0; i < 8; ++i) {
    int m = m0 + i;
    if (m == 0) { vp[i] = f2bf(xs[1024]); vm[i] = 0; }
    else {
      float a = xs[m], r = xs[2048 - m];
      vp[i] = f2bf(a + r);
      vm[i] = f2bf(a - r);
    }
  }
  *(u16x8*)(outp + m0) = vp;
  *(u16x8*)(outp + 1024 + m0) = vm;
}

// ==== fold main: 256rows x 256j, K'=1024, BK=32, tri-buffer, 1 bar/tile ===
// LDS tiles pair-swizzled (2-way bank alias = free). A blob pre-swizzled in
// global; B staged with inverse-swizzled per-lane source (m173).
template <bool USE_SLAB>
__global__ __launch_bounds__(512, 2) void gammatone_fold(
    const char* __restrict__ ub, const char* __restrict__ wbt2,
    const char* __restrict__ gb, float* __restrict__ dst) {
  __shared__ __align__(16) char smem[147456];   // 3 x 48KB {A16K, B+16K, B-16K}

  const int tid = threadIdx.x;
  const int w = tid >> 6, l = tid & 63;
  const int lgrp = l >> 4, l15 = l & 15;
  const int fh = w >> 2, jq = w & 3;            // f-half, j-quarter

  // bijective XCD chunking, j-major order (fb fastest)
  const int orig = blockIdx.x;
  const int xcd = orig & 7, slot = orig >> 3;
  const int q = NWG / 8, r = NWG & 7;           // 121, 4
  const int wkid = (xcd < r ? xcd * (q + 1) : r * (q + 1) + (xcd - r) * q) + slot;
  const int jb = wkid / NT_F;
  const int fb = wkid - jb * NT_F;
  const int j0 = jb * 256;
  const int f0 = fb * 128;

  // staging: wave w stages A bytes [w*2048,+2048) (2 glds) and sign ssn=w>>2,
  // B quarter q4=w&3 (4 glds). LDS dest linear; B source inverse-swizzled:
  // dest L in sign-tile -> jp=L>>7, s=(L>>4)&7; v=s^(jp&7); j=jp*2+(v>>2); ks=v&3
  const int ssn = w >> 2, q4 = w & 3;
  const int aoff_sta = w * 2048 + l * 16;
  const int boff_sta = 16384 + ssn * 16384 + q4 * 4096 + l * 16;
  const int vsw = (l & 7) ^ (l >> 3);
  const char* bsrc[4];
#pragma unroll
  for (int i = 0; i < 4; ++i) {
    int col = j0 + q4 * 64 + i * 16 + (l >> 3) * 2 + (vsw >> 2);
    bsrc[i] = ub + (size_t)col * 4096 + ssn * 2048 + (vsw & 3) * 16;
  }
  const char* wbtA = wbt2 + (size_t)fb * 524288;

#define STAGEF(kkt, off) do {                                               \
    const char* ga_ = wbtA + (size_t)(kkt) * 16384 + aoff_sta;              \
    GLD16(ga_,        smem + (off) + aoff_sta);                             \
    GLD16(ga_ + 1024, smem + (off) + aoff_sta + 1024);                      \
    GLD16(bsrc[0] + (size_t)(kkt) * 64, smem + (off) + boff_sta);           \
    GLD16(bsrc[1] + (size_t)(kkt) * 64, smem + (off) + boff_sta + 1024);    \
    GLD16(bsrc[2] + (size_t)(kkt) * 64, smem + (off) + boff_sta + 2048);    \
    GLD16(bsrc[3] + (size_t)(kkt) * 64, smem + (off) + boff_sta + 3072);    \
  } while (0)

  // swizzled per-lane read offsets: row r, k-slot lgrp ->
  // (r>>1)*128 + ((lgrp|((r&1)<<2)) ^ ((r>>1)&7))*16 ; (r>>1)&7 == l15>>1 here
  const int slb = ((lgrp | ((l15 & 1) << 2)) ^ (l15 >> 1)) << 4;
  int aoff[8], bpo[4], bmo[4];
#pragma unroll
  for (int m = 0; m < 8; ++m)
    aoff[m] = ((m >> 2) * 64 + fh * 32 + (m & 3) * 8 + (l15 >> 1)) * 128 + slb;
#pragma unroll
  for (int n = 0; n < 4; ++n) {
    bpo[n] = 16384 + (jq * 32 + n * 8 + (l15 >> 1)) * 128 + slb;
    bmo[n] = bpo[n] + 16384;
  }

  // prologue: tiles 0,1 -> buf0,buf1
  STAGEF(0, 0);
  STAGEF(1, 49152);
  asm volatile("s_waitcnt vmcnt(6)" ::: "memory");
  asm volatile("s_barrier" ::: "memory");

  f32x4 acc[8][4];
#pragma unroll
  for (int m = 0; m < 8; ++m)
#pragma unroll
    for (int n = 0; n < 4; ++n) acc[m][n] = (f32x4){0.f, 0.f, 0.f, 0.f};

  unsigned b0 = 0, b1 = 49152, b2 = 98304;
  for (int kk = 0; kk < 32; ++kk) {
    bf16x8 av[8], bp[4], bm[4];
#pragma unroll
    for (int m = 0; m < 8; ++m) av[m] = *(const bf16x8*)(smem + b0 + aoff[m]);
#pragma unroll
    for (int n = 0; n < 4; ++n) {
      bp[n] = *(const bf16x8*)(smem + b0 + bpo[n]);
      bm[n] = *(const bf16x8*)(smem + b0 + bmo[n]);
    }
    if (kk < 30) STAGEF(kk + 2, b2);
    __builtin_amdgcn_s_setprio(1);
#pragma unroll
    for (int m = 0; m < 4; ++m)
#pragma unroll
      for (int n = 0; n < 4; ++n) {
        acc[m][n]     = mfma16(av[m],     bp[n], acc[m][n]);
        acc[m + 4][n] = mfma16(av[m + 4], bm[n], acc[m + 4][n]);
      }
    __builtin_amdgcn_s_setprio(0);
    if (kk < 30)       asm volatile("s_waitcnt vmcnt(6)" ::: "memory");
    else if (kk == 30) asm volatile("s_waitcnt vmcnt(0)" ::: "memory");
    asm volatile("s_barrier" ::: "memory");
    unsigned t = b0; b0 = b1; b1 = b2; b2 = t;
  }

  // spec = s^2 + c^2 -> LDS [256 j][128 f] bf16, swizzled (256B rows)
#pragma unroll
  for (int m = 0; m < 4; ++m) {
    int fi = fh * 64 + m * 16 + lgrp * 4;
#pragma unroll
    for (int n = 0; n < 4; ++n) {
      int j = jq * 64 + n * 16 + l15;
      f32x4 c = acc[m][n], s = acc[m + 4][n];
      uint32_t lo = (uint32_t)f2bf(s.x * s.x + c.x * c.x) |
                    ((uint32_t)f2bf(s.y * s.y + c.y * c.y) << 16);
      uint32_t hi = (uint32_t)f2bf(s.z * s.z + c.z * c.z) |
                    ((uint32_t)f2bf(s.w * s.w + c.w * c.w) << 16);
      int off = j * 256 + ((fi * 2) ^ ((j & 7) << 4));
      *(u32x2*)(smem + off) = (u32x2){lo, hi};
    }
  }
  __syncthreads();

  // second GEMM: out_part[64][256j] = G[64][f0:+128] x spec[128][256]
  f32x4 acc2[4][2];
#pragma unroll
  for (int m = 0; m < 4; ++m) {
    acc2[m][0] = (f32x4){0.f, 0.f, 0.f, 0.f};
    acc2[m][1] = (f32x4){0.f, 0.f, 0.f, 0.f};
  }
  const int jw = w * 32;
#pragma unroll
  for (int ks = 0; ks < 4; ++ks) {
    bf16x8 gf[4], sf[2];
#pragma unroll
    for (int m2 = 0; m2 < 4; ++m2) {
      int grow = m2 * 16 + l15;
      gf[m2] = *(const bf16x8*)(gb + ((size_t)grow * FPAD + f0 + ks * 32 + lgrp * 8) * 2);
    }
#pragma unroll
    for (int nf = 0; nf < 2; ++nf) {
      int j = jw + nf * 16 + l15;
      sf[nf] = *(const bf16x8*)(smem + j * 256 + (((ks * 32 + lgrp * 8) * 2) ^ ((j & 7) << 4)));
    }
#pragma unroll
    for (int m2 = 0; m2 < 4; ++m2)
#pragma unroll
      for (int nf = 0; nf < 2; ++nf)
        acc2[m2][nf] = mfma16(gf[m2], sf[nf], acc2[m2][nf]);
  }

#pragma unroll
  for (int nf = 0; nf < 2; ++nf) {
    int jg = j0 + jw + nf * 16 + l15;
    if (USE_SLAB) {
      float* sl = dst + ((size_t)fb * NB) * JPAD + jg;
#pragma unroll
      for (int m2 = 0; m2 < 4; ++m2)
#pragma unroll
        for (int r2 = 0; r2 < 4; ++r2) {
          int nout = m2 * 16 + lgrp * 4 + r2;
          sl[(size_t)nout * JPAD] = acc2[m2][nf][r2];
        }
    } else if (jg < J_TOT) {
      int b = jg / T_FR;
      int t = jg - b * T_FR;
      float* ob = dst + (size_t)(b * NB) * T_FR + t;
#pragma unroll
      for (int m2 = 0; m2 < 4; ++m2)
#pragma unroll
        for (int r2 = 0; r2 < 4; ++r2) {
          int nout = m2 * 16 + lgrp * 4 + r2;
          atomicAdd(ob + (size_t)nout * T_FR, acc2[m2][nf][r2]);
        }
    }
  }
}

// ==== fallback path (round-5 kernels, verbatim) ===========================

__global__ __launch_bounds__(256) void build_xbp(const float* __restrict__ x,
                                                 uint16_t* __restrict__ xbp) {
  int i = blockIdx.x * 256 + threadIdx.x;
  int b = i / LP;
  int p = i - b * LP;
  xbp[i] = f2bf(x[b * L_AUD + refl(p)]);
}

__global__ __launch_bounds__(256) void build_wbtf(const float* __restrict__ wsin,
                                                  const float* __restrict__ wcos,
                                                  uint16_t* __restrict__ wbt) {
  int idx = blockIdx.x * 256 + threadIdx.x;
  int e = idx & 7;
  int l = (idx >> 3) & 63;
  int s = (idx >> 9) & 1;
  int fm = (idx >> 10) & 15;
  int kkt = (idx >> 14) & 31;
  int fb = idx >> 19;
  int tr = fm * 16 + (l & 15);
  int k = kkt * 64 + s * 32 + ((l >> 4) << 3) + e;
  int plane = (tr >> 6) & 1;
  int f = fb * 128 + ((tr >> 7) << 6) + (tr & 63);
  float v = (f < F_BINS) ? (plane ? wcos[f * NFFT + k] : wsin[f * NFFT + k]) : 0.0f;
  wbt[idx] = f2bf(v);
}

__device__ __forceinline__ void load_a2(bf16x8 (&d)[2][2], const char* p) {
  d[0][0] = *(const bf16x8*)(p);
  d[0][1] = *(const bf16x8*)(p + 1024);
  d[1][0] = *(const bf16x8*)(p + 2048);
  d[1][1] = *(const bf16x8*)(p + 3072);
}
__device__ __forceinline__ void load_b4(bf16x8 (&dst)[4][2], const char* p,
                                        int k0, int k1) {
#pragma unroll
  for (int n = 0; n < 4; ++n) {
    dst[n][0] = *(const bf16x8*)(p + n * 2048 + k0);
    dst[n][1] = *(const bf16x8*)(p + n * 2048 + k1);
  }
}
__device__ __forceinline__ void mfma_pair(f32x4 (*ac)[4],
                                          const bf16x8 (&av)[2][2],
                                          const bf16x8 (&bv)[4][2]) {
#pragma unroll
  for (int m = 0; m < 2; ++m)
#pragma unroll
    for (int n = 0; n < 4; ++n) {
      ac[m][n] = mfma16(av[m][0], bv[n][0], ac[m][n]);
      ac[m][n] = mfma16(av[m][1], bv[n][1], ac[m][n]);
    }
}

template <bool USE_SLAB>
__global__ __launch_bounds__(512, 2) void gammatone_fb(
    const char* __restrict__ xbp, const char* __restrict__ wbt,
    const char* __restrict__ gb, float* __restrict__ dst) {
  __shared__ __align__(16) char smem[65536];

  const int tid = threadIdx.x;
  const int w = tid >> 6, l = tid & 63;
  const int lgrp = l >> 4, l15 = l & 15;
  const int wr = w >> 2, wc = w & 3;

  const int orig = blockIdx.y * NT_J + blockIdx.x;
  const int xcd = orig & 7, slot = orig >> 3;
  const int q = NWG / 8, r = NWG & 7;
  const int wkid = (xcd < r ? xcd * (q + 1) : r * (q + 1) + (xcd - r) * q) + slot;
  const int fb = wkid / NT_J;
  const int jb = wkid - fb * NT_J;
  const int j0 = jb * 256;
  const int f0 = fb * 128;

  const int xr = (((tid & 7) << 4)) ^ ((((tid >> 3) & 7)) << 4);
  size_t fbase[2][2];
#pragma unroll
  for (int h = 0; h < 2; ++h)
#pragma unroll
    for (int i = 0; i < 2; ++i) {
      int col = j0 + h * 128 + i * 64 + (tid >> 3);
      if (col > J_TOT - 1) col = J_TOT - 1;
      int b = col / T_FR;
      int t = col - b * T_FR;
      fbase[h][i] = (size_t)b * ROWB + (size_t)t * 1024 + (size_t)xr;
    }

#define STAGE_B2(kkt, buf) do {                                             \
    char* d0_ = smem + (buf) * 32768;                                       \
    char* d1_ = smem + (buf) * 32768 + 16384;                               \
    GLD16(xbp + fbase[0][0] + (size_t)(kkt) * 128, d0_ + w * 1024 + l * 16);\
    GLD16(xbp + fbase[0][1] + (size_t)(kkt) * 128, d0_ + 8192 + w * 1024 + l * 16);\
    GLD16(xbp + fbase[1][0] + (size_t)(kkt) * 128, d1_ + w * 1024 + l * 16);\
    GLD16(xbp + fbase[1][1] + (size_t)(kkt) * 128, d1_ + 8192 + w * 1024 + l * 16);\
  } while (0)

  const int albase = l15 * 128;
  const int xa = (l15 & 7) << 4;
  const int k0 = (lgrp * 16) ^ xa;
  const int k1 = (64 + lgrp * 16) ^ xa;
  const int jrb = (wc & 1) * 64;
  const char* Bb0 = smem + (wc >> 1) * 16384 + jrb * 128 + albase;
  const char* Bb1 = Bb0 + 32768;
  const char* wbt_a = wbt + (size_t)fb * 32 * 32768 + wr * 16384 + (size_t)l * 16;

  STAGE_B2(0, 0);
  STAGE_B2(1, 1);
  asm volatile("s_waitcnt vmcnt(0)" ::: "memory");
  __builtin_amdgcn_s_barrier();

  f32x4 acc[8][4];
#pragma unroll
  for (int m = 0; m < 8; ++m)
#pragma unroll
    for (int n = 0; n < 4; ++n) acc[m][n] = (f32x4){0.f, 0.f, 0.f, 0.f};

  bf16x8 bvA[4][2], bvB[4][2], av0[2][2], av1[2][2];
  load_b4(bvA, Bb0, k0, k1);
  load_a2(av0, wbt_a);
  asm volatile("s_waitcnt lgkmcnt(0)" ::: "memory");
  __builtin_amdgcn_s_barrier();

#define SP1 __builtin_amdgcn_s_setprio(1)
#define SP0 __builtin_amdgcn_s_setprio(0)

#define TILEFB(KK, bvC, bvN, BbN, STG, NXT) do {                            \
    const char* aT = wbt_a + (size_t)(KK) * 32768;                          \
    if (STG) STAGE_B2((KK) + 2, (KK) & 1);                                  \
    load_a2(av1, aT + 2 * 2048);                                            \
    SP1; mfma_pair(&acc[0], av0, bvC); SP0;                                 \
    load_a2(av0, aT + 4 * 2048);                                            \
    SP1; mfma_pair(&acc[2], av1, bvC); SP0;                                 \
    load_a2(av1, aT + 6 * 2048);                                            \
    if (NXT) load_b4(bvN, BbN, k0, k1);                                     \
    SP1; mfma_pair(&acc[4], av0, bvC); SP0;                                 \
    if (NXT) load_a2(av0, wbt_a + (size_t)((KK) + 1) * 32768);              \
    SP1; mfma_pair(&acc[6], av1, bvC); SP0;                                 \
    asm volatile("s_waitcnt lgkmcnt(0)" ::: "memory");                      \
    __builtin_amdgcn_s_barrier();                                           \
  } while (0)

  for (int kk = 0; kk < 30; kk += 2) {
    TILEFB(kk,     bvA, bvB, Bb1, 1, 1);
    TILEFB(kk + 1, bvB, bvA, Bb0, 1, 1);
  }
  TILEFB(30, bvA, bvB, Bb1, 0, 1);
  TILEFB(31, bvB, bvA, Bb0, 0, 0);

  __syncthreads();
#pragma unroll
  for (int m = 0; m < 4; ++m) {
    int fi = wr * 64 + m * 16 + lgrp * 4;
#pragma unroll
    for (int n = 0; n < 4; ++n) {
      int j = wc * 64 + n * 16 + l15;
      f32x4 s = acc[m][n], c = acc[m + 4][n];
      uint32_t lo = (uint32_t)f2bf(s.x * s.x + c.x * c.x) |
                    ((uint32_t)f2bf(s.y * s.y + c.y * c.y) << 16);
      uint32_t hi = (uint32_t)f2bf(s.z * s.z + c.z * c.z) |
                    ((uint32_t)f2bf(s.w * s.w + c.w * c.w) << 16);
      int off = j * 256 + ((fi * 2) ^ ((j & 7) << 4));
      *(u32x2*)(smem + off) = (u32x2){lo, hi};
    }
  }
  __syncthreads();

  f32x4 acc2[4][2];
#pragma unroll
  for (int m = 0; m < 4; ++m) {
    acc2[m][0] = (f32x4){0.f, 0.f, 0.f, 0.f};
    acc2[m][1] = (f32x4){0.f, 0.f, 0.f, 0.f};
  }
  const int jw = w * 32;
#pragma unroll
  for (int ks = 0; ks < 4; ++ks) {
    bf16x8 gf[4], sf[2];
#pragma unroll
    for (int m2 = 0; m2 < 4; ++m2) {
      int grow = m2 * 16 + l15;
      gf[m2] = *(const bf16x8*)(gb + ((size_t)grow * FPAD + f0 + ks * 32 + lgrp * 8) * 2);
    }
#pragma unroll
    for (int nf = 0; nf < 2; ++nf) {
      int j = jw + nf * 16 + l15;
      sf[nf] = *(const bf16x8*)(smem + j * 256 + (((ks * 32 + lgrp * 8) * 2) ^ ((j & 7) << 4)));
    }
#pragma unroll
    for (int m2 = 0; m2 < 4; ++m2)
#pragma unroll
      for (int nf = 0; nf < 2; ++nf)
        acc2[m2][nf] = mfma16(gf[m2], sf[nf], acc2[m2][nf]);
  }

#pragma unroll
  for (int nf = 0; nf < 2; ++nf) {
    int jg = j0 + jw + nf * 16 + l15;
    if (USE_SLAB) {
      float* sl = dst + ((size_t)fb * NB) * JPAD + jg;
#pragma unroll
      for (int m2 = 0; m2 < 4; ++m2)
#pragma unroll
        for (int r2 = 0; r2 < 4; ++r2) {
          int nout = m2 * 16 + lgrp * 4 + r2;
          sl[(size_t)nout * JPAD] = acc2[m2][nf][r2];
        }
    } else if (jg < J_TOT) {
      int b = jg / T_FR;
      int t = jg - b * T_FR;
      float* ob = dst + (size_t)(b * NB) * T_FR + t;
#pragma unroll
      for (int m2 = 0; m2 < 4; ++m2)
#pragma unroll
        for (int r2 = 0; r2 < 4; ++r2) {
          int nout = m2 * 16 + lgrp * 4 + r2;
          atomicAdd(ob + (size_t)nout * T_FR, acc2[m2][nf][r2]);
        }
    }
  }
}

// ==== launcher ============================================================
extern "C" void kernel_launch(void* const* d_in, const int* in_sizes, int n_in,
                              void* d_out, int out_size, void* d_ws, size_t ws_size,
                              hipStream_t stream) {
  (void)in_sizes; (void)n_in;
  const float* x    = (const float*)d_in[0];
  const float* wsin = (const float*)d_in[1];
  const float* wcos = (const float*)d_in[2];
  const float* g    = (const float*)d_in[3];
  char* ws = (char*)d_ws;

  if (ws_size >= (size_t)WS_FOLD) {
    uint16_t* wbt2 = (uint16_t*)(ws + W2_OFF);
    uint16_t* gbp  = (uint16_t*)(ws + GB2_OFF);
    uint16_t* ub   = (uint16_t*)(ws + UB_OFF);
    build_wbt2<<<(W2_BYTES / 2) / 256, 256, 0, stream>>>(wsin, wcos, wbt2);
    build_gb<<<(NB * FPAD) / 256, 256, 0, stream>>>(g, gbp);
    build_ub<<<JPAD, 128, 0, stream>>>(x, ub);
    if (ws_size >= (size_t)WS_FOLD_SLAB) {
      float* slab = (float*)(ws + WS_FOLD);
      gammatone_fold<true><<<NWG, 512, 0, stream>>>(
          (const char*)ub, (const char*)wbt2, (const char*)gbp, slab);
      reduce9<<<(J_TOT * NB + 255) / 256, 256, 0, stream>>>(slab, (float*)d_out);
    } else {
      (void)hipMemsetAsync(d_out, 0, (size_t)out_size * sizeof(float), stream);
      gammatone_fold<false><<<NWG, 512, 0, stream>>>(
          (const char*)ub, (const char*)wbt2, (const char*)gbp, (float*)d_out);
    }
    return;
  }

  // fallback: round-5 path
  if (ws_size < (size_t)FB_WS_NEED) return;
  uint16_t* xbp = (uint16_t*)(ws + FB_XBP_OFF);
  uint16_t* wbt = (uint16_t*)(ws + FB_WBT_OFF);
  uint16_t* gbp = (uint16_t*)(ws + FB_GB_OFF);
  build_xbp<<<(B_SZ * LP) / 256, 256, 0, stream>>>(x, xbp);
  build_wbtf<<<(FB_WBT_BYTES / 2) / 256, 256, 0, stream>>>(wsin, wcos, wbt);
  build_gb<<<(NB * FPAD) / 256, 256, 0, stream>>>(g, gbp);
  if (ws_size >= (size_t)FB_WS_BIG) {
    float* slab = (float*)(ws + FB_SLAB_OFF);
    gammatone_fb<true><<<dim3(FB_NT_J, NT_F), 512, 0, stream>>>(
        (const char*)xbp, (const char*)wbt, (const char*)gbp, slab);
    reduce9<<<(J_TOT * NB + 255) / 256, 256, 0, stream>>>(slab, (float*)d_out);
  } else {
    (void)hipMemsetAsync(d_out, 0, (size_t)out_size * sizeof(float), stream);
    gammatone_fb<false><<<dim3(FB_NT_J, NT_F), 512, 0, stream>>>(
        (const char*)xbp, (const char*)wbt, (const char*)gbp, (float*)d_out);
  }
}